// Round 1
// baseline (2384.709 us; speedup 1.0000x reference)
//
#include <hip/hip_runtime.h>

#define DIM 512
#define HEADS 8
#define HD 64
#define NB 8
#define NS 2048
#define SCALE_INV 0.125f
#define NEG_BIG -1e30f

__device__ __forceinline__ float elu_f(float x) {
    return x > 0.0f ? x : (__expf(x) - 1.0f);
}

// ---------------------------------------------------------------------------
// QKV projection: Y = x @ Wqkv^T + bqkv, de-interleaved into Q/K/V [B,H,S,64]
// V gets ELU applied. 64x64 tile, BK=16, 256 threads, 4x4 per thread.
// ---------------------------------------------------------------------------
__global__ __launch_bounds__(256) void qkv_gemm(
    const float* __restrict__ x, const float* __restrict__ W,
    const float* __restrict__ bias,
    float* __restrict__ Q, float* __restrict__ K, float* __restrict__ V)
{
    __shared__ float As[16][68];   // [k][m], pad 68 keeps float4 alignment
    __shared__ float Bs[16][68];   // [k][n]
    const int t = threadIdx.x;
    const int tx = t & 15, ty = t >> 4;
    const int m0 = blockIdx.x * 64;
    const int n0 = blockIdx.y * 64;
    float acc[4][4] = {};
    for (int k0 = 0; k0 < DIM; k0 += 16) {
        #pragma unroll
        for (int i = 0; i < 4; ++i) {
            int idx = i * 256 + t;
            int r = idx >> 4, c = idx & 15;
            As[c][r] = x[(size_t)(m0 + r) * DIM + k0 + c];
            Bs[c][r] = W[(size_t)(n0 + r) * DIM + k0 + c];
        }
        __syncthreads();
        #pragma unroll
        for (int kk = 0; kk < 16; ++kk) {
            float4 a4 = *(const float4*)&As[kk][ty * 4];
            float4 b4 = *(const float4*)&Bs[kk][tx * 4];
            float a[4] = {a4.x, a4.y, a4.z, a4.w};
            float b[4] = {b4.x, b4.y, b4.z, b4.w};
            #pragma unroll
            for (int i = 0; i < 4; ++i)
                #pragma unroll
                for (int j = 0; j < 4; ++j)
                    acc[i][j] += a[i] * b[j];
        }
        __syncthreads();
    }
    #pragma unroll
    for (int i = 0; i < 4; ++i) {
        int m = m0 + ty * 4 + i;
        int b = m >> 11;            // / NS
        int s = m & (NS - 1);
        #pragma unroll
        for (int j = 0; j < 4; ++j) {
            int n = n0 + tx * 4 + j;
            float y = acc[i][j] + bias[n];
            // torch-reshape interleave: n -> (h, d, which)
            int h  = n / 192;
            int rr = n - h * 192;
            int d  = rr / 3;
            int w  = rr - d * 3;
            size_t off = ((size_t)(b * HEADS + h) * NS + s) * HD + d;
            if      (w == 0) Q[off] = y;
            else if (w == 1) K[off] = y;
            else             V[off] = elu_f(y);
        }
    }
}

// ---------------------------------------------------------------------------
// Flash attention: one block per (b, h, 64-row q-tile). Online softmax.
// P-tile aliases K-tile LDS (scores are in registers when P is written).
// ---------------------------------------------------------------------------
__global__ __launch_bounds__(256) void attn_flash(
    const float* __restrict__ Q, const float* __restrict__ K,
    const float* __restrict__ V, const int* __restrict__ mask,
    float* __restrict__ O)
{
    __shared__ float Qs[64][68];
    __shared__ float KP[64][68];   // K tile, then reused as P tile
    __shared__ float Vs[64][68];
    __shared__ float red[64][17];
    __shared__ float msk[64];
    const int t = threadIdx.x;
    const int tx = t & 15, ty = t >> 4;
    const int bid = blockIdx.x;
    const int qt = bid & 31;
    const int h  = (bid >> 5) & 7;
    const int b  = bid >> 8;
    const size_t base = (size_t)(b * HEADS + h) * NS * HD;
    const int q0 = qt * 64;

    #pragma unroll
    for (int i = 0; i < 16; ++i) {
        int idx = i * 256 + t;
        int r = idx >> 6, c = idx & 63;
        Qs[r][c] = Q[base + (size_t)(q0 + r) * HD + c];
    }
    float m_i[4], l_i[4];
    #pragma unroll
    for (int i = 0; i < 4; ++i) { m_i[i] = NEG_BIG; l_i[i] = 0.0f; }
    float o[4][4] = {};

    for (int kt = 0; kt < 32; ++kt) {
        const int k0 = kt * 64;
        __syncthreads();   // protect KP/Vs/msk vs previous iteration reads
        #pragma unroll
        for (int i = 0; i < 16; ++i) {
            int idx = i * 256 + t;
            int r = idx >> 6, c = idx & 63;
            KP[r][c] = K[base + (size_t)(k0 + r) * HD + c];
            Vs[r][c] = V[base + (size_t)(k0 + r) * HD + c];
        }
        if (t < 64) msk[t] = mask[b * NS + k0 + t] ? NEG_BIG : 0.0f;
        __syncthreads();

        // S = Q K^T (64x64), 4x4 per thread, float4 over d
        float s[4][4] = {};
        for (int d = 0; d < 64; d += 4) {
            float4 a[4], bb[4];
            #pragma unroll
            for (int i = 0; i < 4; ++i) a[i]  = *(const float4*)&Qs[ty * 4 + i][d];
            #pragma unroll
            for (int j = 0; j < 4; ++j) bb[j] = *(const float4*)&KP[tx * 4 + j][d];
            #pragma unroll
            for (int i = 0; i < 4; ++i)
                #pragma unroll
                for (int j = 0; j < 4; ++j)
                    s[i][j] += a[i].x * bb[j].x + a[i].y * bb[j].y
                             + a[i].z * bb[j].z + a[i].w * bb[j].w;
        }
        #pragma unroll
        for (int i = 0; i < 4; ++i)
            #pragma unroll
            for (int j = 0; j < 4; ++j)
                s[i][j] = s[i][j] * SCALE_INV + msk[tx * 4 + j];

        // row max across the 16 tx threads
        #pragma unroll
        for (int i = 0; i < 4; ++i) {
            float lm = fmaxf(fmaxf(s[i][0], s[i][1]), fmaxf(s[i][2], s[i][3]));
            red[ty * 4 + i][tx] = lm;
        }
        __syncthreads();
        float mnew[4], alpha[4];
        #pragma unroll
        for (int i = 0; i < 4; ++i) {
            float mt = red[ty * 4 + i][0];
            #pragma unroll
            for (int jj = 1; jj < 16; ++jj) mt = fmaxf(mt, red[ty * 4 + i][jj]);
            float mn = fmaxf(m_i[i], mt);
            alpha[i] = __expf(m_i[i] - mn);   // first tile: exp(-1e30-mn)=0
            mnew[i] = mn;
            m_i[i] = mn;
        }
        // P = exp(S - mnew): write into KP (all score reads of KP are done)
        float lsum[4];
        #pragma unroll
        for (int i = 0; i < 4; ++i) {
            lsum[i] = 0.0f;
            #pragma unroll
            for (int j = 0; j < 4; ++j) {
                float p = __expf(s[i][j] - mnew[i]);
                KP[ty * 4 + i][tx * 4 + j] = p;
                lsum[i] += p;
            }
        }
        __syncthreads();   // P visible; red max-reads done
        #pragma unroll
        for (int i = 0; i < 4; ++i) red[ty * 4 + i][tx] = lsum[i];
        __syncthreads();
        #pragma unroll
        for (int i = 0; i < 4; ++i) {
            float ts = 0.0f;
            #pragma unroll
            for (int jj = 0; jj < 16; ++jj) ts += red[ty * 4 + i][jj];
            l_i[i] = alpha[i] * l_i[i] + ts;
        }
        // O = alpha*O + P @ V
        #pragma unroll
        for (int i = 0; i < 4; ++i)
            #pragma unroll
            for (int j = 0; j < 4; ++j)
                o[i][j] *= alpha[i];
        for (int k = 0; k < 64; k += 4) {
            float4 p[4], vv[4];
            #pragma unroll
            for (int i = 0; i < 4; ++i)  p[i]  = *(const float4*)&KP[ty * 4 + i][k];
            #pragma unroll
            for (int kk = 0; kk < 4; ++kk) vv[kk] = *(const float4*)&Vs[k + kk][tx * 4];
            #pragma unroll
            for (int i = 0; i < 4; ++i) {
                o[i][0] += p[i].x * vv[0].x + p[i].y * vv[1].x + p[i].z * vv[2].x + p[i].w * vv[3].x;
                o[i][1] += p[i].x * vv[0].y + p[i].y * vv[1].y + p[i].z * vv[2].y + p[i].w * vv[3].y;
                o[i][2] += p[i].x * vv[0].z + p[i].y * vv[1].z + p[i].z * vv[2].z + p[i].w * vv[3].z;
                o[i][3] += p[i].x * vv[0].w + p[i].y * vv[1].w + p[i].z * vv[2].w + p[i].w * vv[3].w;
            }
        }
    }
    // epilogue: O[b, q, h*64 + d] = o / l
    #pragma unroll
    for (int i = 0; i < 4; ++i) {
        float inv = 1.0f / l_i[i];   // key 0 always unmasked -> l > 0
        int q = q0 + ty * 4 + i;
        size_t rowoff = ((size_t)(b * NS + q)) * DIM + h * HD + tx * 4;
        #pragma unroll
        for (int j = 0; j < 4; ++j)
            O[rowoff + j] = o[i][j] * inv;
    }
}

// ---------------------------------------------------------------------------
// Out projection: Z = ATT @ Wout^T + bout
// ---------------------------------------------------------------------------
__global__ __launch_bounds__(256) void out_gemm(
    const float* __restrict__ A, const float* __restrict__ W,
    const float* __restrict__ bias, float* __restrict__ Z)
{
    __shared__ float As[16][68];
    __shared__ float Bs[16][68];
    const int t = threadIdx.x;
    const int tx = t & 15, ty = t >> 4;
    const int m0 = blockIdx.x * 64;
    const int n0 = blockIdx.y * 64;
    float acc[4][4] = {};
    for (int k0 = 0; k0 < DIM; k0 += 16) {
        #pragma unroll
        for (int i = 0; i < 4; ++i) {
            int idx = i * 256 + t;
            int r = idx >> 4, c = idx & 15;
            As[c][r] = A[(size_t)(m0 + r) * DIM + k0 + c];
            Bs[c][r] = W[(size_t)(n0 + r) * DIM + k0 + c];
        }
        __syncthreads();
        #pragma unroll
        for (int kk = 0; kk < 16; ++kk) {
            float4 a4 = *(const float4*)&As[kk][ty * 4];
            float4 b4 = *(const float4*)&Bs[kk][tx * 4];
            float a[4] = {a4.x, a4.y, a4.z, a4.w};
            float b[4] = {b4.x, b4.y, b4.z, b4.w};
            #pragma unroll
            for (int i = 0; i < 4; ++i)
                #pragma unroll
                for (int j = 0; j < 4; ++j)
                    acc[i][j] += a[i] * b[j];
        }
        __syncthreads();
    }
    #pragma unroll
    for (int i = 0; i < 4; ++i) {
        int m = m0 + ty * 4 + i;
        #pragma unroll
        for (int j = 0; j < 4; ++j) {
            int n = n0 + tx * 4 + j;
            Z[(size_t)m * DIM + n] = acc[i][j] + bias[n];
        }
    }
}

// ---------------------------------------------------------------------------
// LayerNorm + ELU: one block of 256 threads per row of 512.
// ---------------------------------------------------------------------------
__global__ __launch_bounds__(256) void ln_elu(
    const float* __restrict__ Z, const float* __restrict__ g,
    const float* __restrict__ bt, float* __restrict__ out)
{
    const int row = blockIdx.x;
    const float* z = Z + (size_t)row * DIM;
    const int t = threadIdx.x;
    float v0 = z[t], v1 = z[t + 256];
    float s  = v0 + v1;
    float ss = v0 * v0 + v1 * v1;
    #pragma unroll
    for (int off = 32; off > 0; off >>= 1) {
        s  += __shfl_down(s, off);
        ss += __shfl_down(ss, off);
    }
    __shared__ float rs[4], rss[4];
    int wid = t >> 6, lane = t & 63;
    if (lane == 0) { rs[wid] = s; rss[wid] = ss; }
    __syncthreads();
    float S1 = rs[0] + rs[1] + rs[2] + rs[3];
    float S2 = rss[0] + rss[1] + rss[2] + rss[3];
    float mu  = S1 * (1.0f / DIM);
    float var = S2 * (1.0f / DIM) - mu * mu;
    float rstd = rsqrtf(var + 1e-5f);
    float y0 = (v0 - mu) * rstd * g[t]       + bt[t];
    float y1 = (v1 - mu) * rstd * g[t + 256] + bt[t + 256];
    out[(size_t)row * DIM + t]       = elu_f(y0);
    out[(size_t)row * DIM + t + 256] = elu_f(y1);
}

extern "C" void kernel_launch(void* const* d_in, const int* in_sizes, int n_in,
                              void* d_out, int out_size, void* d_ws, size_t ws_size,
                              hipStream_t stream)
{
    const float* x    = (const float*)d_in[0];
    const int*   mask = (const int*)d_in[1];
    const float* Wqkv = (const float*)d_in[2];
    const float* bqkv = (const float*)d_in[3];
    const float* Wout = (const float*)d_in[4];
    const float* bout = (const float*)d_in[5];
    const float* ln_g = (const float*)d_in[6];
    const float* ln_b = (const float*)d_in[7];
    float* out = (float*)d_out;
    float* ws  = (float*)d_ws;

    const size_t QSZ = (size_t)NB * HEADS * NS * HD;   // 8388608 floats
    float* Q    = ws;
    float* Kbuf = ws + QSZ;
    float* Vbuf = ws + 2 * QSZ;
    float* ATT  = ws + 3 * QSZ;
    float* Zbuf = Q;   // Q is dead after attention

    dim3 g1(256, 24);
    qkv_gemm<<<g1, 256, 0, stream>>>(x, Wqkv, bqkv, Q, Kbuf, Vbuf);
    attn_flash<<<2048, 256, 0, stream>>>(Q, Kbuf, Vbuf, mask, ATT);
    dim3 g3(256, 8);
    out_gemm<<<g3, 256, 0, stream>>>(ATT, Wout, bout, Zbuf);
    ln_elu<<<NB * NS, 256, 0, stream>>>(Zbuf, ln_g, ln_b, out);
}

// Round 2
// 789.765 us; speedup vs baseline: 3.0195x; 3.0195x over previous
//
#include <hip/hip_runtime.h>

#define DIM 512
#define HEADS 8
#define HD 64
#define NB 8
#define NS 2048
#define SCALE_INV 0.125f
#define NEG_BIG -1e30f

typedef __attribute__((ext_vector_type(8))) short bf16x8;
typedef __attribute__((ext_vector_type(4))) float f32x4;

__device__ __forceinline__ float elu_f(float x) {
    return x > 0.0f ? x : (__expf(x) - 1.0f);
}

__device__ __forceinline__ short f2bf(float x) {
    union { float f; unsigned u; } v; v.f = x;
    unsigned r = v.u + 0x7FFFu + ((v.u >> 16) & 1u);   // RNE
    return (short)(r >> 16);
}

// ---------------------------------------------------------------------------
// QKV projection: Y = x @ Wqkv^T + bqkv. fp32 compute, epilogue emits bf16:
//   Q,K -> [b,h,s,d],  V -> ELU then TRANSPOSED [b,h,d,s] (for PV B-operand).
// ---------------------------------------------------------------------------
__global__ __launch_bounds__(256) void qkv_gemm(
    const float* __restrict__ x, const float* __restrict__ W,
    const float* __restrict__ bias,
    short* __restrict__ Q, short* __restrict__ K, short* __restrict__ Vt)
{
    __shared__ float As[16][68];
    __shared__ float Bs[16][68];
    const int t = threadIdx.x;
    const int tx = t & 15, ty = t >> 4;
    const int m0 = blockIdx.x * 64;
    const int n0 = blockIdx.y * 64;
    float acc[4][4] = {};
    for (int k0 = 0; k0 < DIM; k0 += 16) {
        #pragma unroll
        for (int i = 0; i < 4; ++i) {
            int idx = i * 256 + t;
            int r = idx >> 4, c = idx & 15;
            As[c][r] = x[(size_t)(m0 + r) * DIM + k0 + c];
            Bs[c][r] = W[(size_t)(n0 + r) * DIM + k0 + c];
        }
        __syncthreads();
        #pragma unroll
        for (int kk = 0; kk < 16; ++kk) {
            float4 a4 = *(const float4*)&As[kk][ty * 4];
            float4 b4 = *(const float4*)&Bs[kk][tx * 4];
            float a[4] = {a4.x, a4.y, a4.z, a4.w};
            float b[4] = {b4.x, b4.y, b4.z, b4.w};
            #pragma unroll
            for (int i = 0; i < 4; ++i)
                #pragma unroll
                for (int j = 0; j < 4; ++j)
                    acc[i][j] += a[i] * b[j];
        }
        __syncthreads();
    }
    #pragma unroll
    for (int i = 0; i < 4; ++i) {
        int m = m0 + ty * 4 + i;
        int b = m >> 11;
        int s = m & (NS - 1);
        #pragma unroll
        for (int j = 0; j < 4; ++j) {
            int n = n0 + tx * 4 + j;
            float y = acc[i][j] + bias[n];
            int h  = n / 192;
            int rr = n - h * 192;
            int d  = rr / 3;
            int w  = rr - d * 3;
            if (w == 2) {
                Vt[((size_t)(b * HEADS + h) * HD + d) * NS + s] = f2bf(elu_f(y));
            } else {
                size_t off = ((size_t)(b * HEADS + h) * NS + s) * HD + d;
                if (w == 0) Q[off] = f2bf(y);
                else        K[off] = f2bf(y);
            }
        }
    }
}

// ---------------------------------------------------------------------------
// Flash attention, bf16 MFMA 16x16x32. One block = (b, h, 64-row q-tile).
// 4 waves; wave w owns q rows [w*16, w*16+16). XOR-swizzled LDS tiles
// (16B blocks, block ^= row&7) -> 2-way max conflicts on ds_read_b128.
// C-layout: col=lane&15, row=quad*4+reg.  A-layout: m=lane&15, k=quad*8+j.
// ---------------------------------------------------------------------------
__global__ __launch_bounds__(256) void attn_mfma(
    const short* __restrict__ Qg, const short* __restrict__ Kg,
    const short* __restrict__ Vg, const int* __restrict__ mask,
    float* __restrict__ O)
{
    __shared__ short Qs[64 * 64];
    __shared__ short Ks[64 * 64];
    __shared__ short Vs[64 * 64];   // [d][k] (Vt tile)
    __shared__ short Ps[64 * 64];   // [q][k]
    __shared__ float msk[64];

    const int t = threadIdx.x;
    const int lane = t & 63;
    const int wv = t >> 6;            // wave 0..3
    const int c = lane & 15;
    const int quad = lane >> 4;
    const int bid = blockIdx.x;
    const int qt = bid & 31;
    const int h  = (bid >> 5) & 7;
    const int b  = bid >> 8;
    const size_t base = (size_t)(b * HEADS + h) * NS * HD;   // same for Q/K/Vt
    const int q0 = qt * 64;

    // stage Q tile (64 rows x 64 bf16), swizzled
    #pragma unroll
    for (int p = 0; p < 2; ++p) {
        int idx = p * 256 + t, r = idx >> 3, cb = idx & 7;
        uint4 v = *(const uint4*)(Qg + base + (size_t)(q0 + r) * HD + cb * 8);
        *(uint4*)&Qs[r * 64 + ((cb ^ (r & 7)) * 8)] = v;
    }
    __syncthreads();

    const int m = wv * 16 + c;        // this lane's A-row (q within tile)
    const bf16x8 aq0 = *(const bf16x8*)&Qs[m * 64 + ((quad       ^ (m & 7)) * 8)];
    const bf16x8 aq1 = *(const bf16x8*)&Qs[m * 64 + (((4 + quad) ^ (m & 7)) * 8)];

    f32x4 o[4];
    #pragma unroll
    for (int dc = 0; dc < 4; ++dc)
        #pragma unroll
        for (int i = 0; i < 4; ++i) o[dc][i] = 0.0f;
    float m_i[4], l_i[4];
    #pragma unroll
    for (int i = 0; i < 4; ++i) { m_i[i] = NEG_BIG; l_i[i] = 0.0f; }

    for (int kt = 0; kt < 32; ++kt) {
        const int k0 = kt * 64;
        __syncthreads();   // previous-iteration Ks/Vs/msk reads complete
        #pragma unroll
        for (int p = 0; p < 2; ++p) {
            int idx = p * 256 + t, r = idx >> 3, cb = idx & 7;
            *(uint4*)&Ks[r * 64 + ((cb ^ (r & 7)) * 8)] =
                *(const uint4*)(Kg + base + (size_t)(k0 + r) * HD + cb * 8);
            *(uint4*)&Vs[r * 64 + ((cb ^ (r & 7)) * 8)] =
                *(const uint4*)(Vg + base + (size_t)r * NS + k0 + cb * 8);
        }
        if (t < 64) msk[t] = mask[b * NS + k0 + t] ? NEG_BIG : 0.0f;
        __syncthreads();

        // ---- S = Q K^T : 4 n-chunks x (K=64 as 2 MFMAs) ----
        f32x4 s4[4];
        #pragma unroll
        for (int nc = 0; nc < 4; ++nc) {
            int kr = nc * 16 + c;
            bf16x8 bk0 = *(const bf16x8*)&Ks[kr * 64 + ((quad       ^ (kr & 7)) * 8)];
            bf16x8 bk1 = *(const bf16x8*)&Ks[kr * 64 + (((4 + quad) ^ (kr & 7)) * 8)];
            f32x4 acc = {0.0f, 0.0f, 0.0f, 0.0f};
            acc = __builtin_amdgcn_mfma_f32_16x16x32_bf16(aq0, bk0, acc, 0, 0, 0);
            acc = __builtin_amdgcn_mfma_f32_16x16x32_bf16(aq1, bk1, acc, 0, 0, 0);
            s4[nc] = acc;
        }
        float bs[4];
        #pragma unroll
        for (int nc = 0; nc < 4; ++nc) bs[nc] = msk[nc * 16 + c];
        #pragma unroll
        for (int nc = 0; nc < 4; ++nc)
            #pragma unroll
            for (int i = 0; i < 4; ++i)
                s4[nc][i] = s4[nc][i] * SCALE_INV + bs[nc];

        // ---- online softmax (rows = quad*4+i, shared by 16 lanes c) ----
        float alpha[4], mn_r[4];
        #pragma unroll
        for (int i = 0; i < 4; ++i) {
            float rmax = fmaxf(fmaxf(s4[0][i], s4[1][i]), fmaxf(s4[2][i], s4[3][i]));
            #pragma unroll
            for (int off = 1; off < 16; off <<= 1)
                rmax = fmaxf(rmax, __shfl_xor(rmax, off));
            float mn = fmaxf(m_i[i], rmax);
            alpha[i] = __expf(m_i[i] - mn);   // tile 0: exp(-1e30 - finite) = 0
            mn_r[i] = mn;
            m_i[i] = mn;
        }
        #pragma unroll
        for (int i = 0; i < 4; ++i) {
            float ls = 0.0f;
            int r = wv * 16 + quad * 4 + i;
            #pragma unroll
            for (int nc = 0; nc < 4; ++nc) {
                float p = __expf(s4[nc][i] - mn_r[i]);
                ls += p;
                int col = nc * 16 + c;
                int cb = col >> 3;
                Ps[r * 64 + ((cb ^ (r & 7)) * 8) + (col & 7)] = f2bf(p);
            }
            #pragma unroll
            for (int off = 1; off < 16; off <<= 1)
                ls += __shfl_xor(ls, off);
            l_i[i] = alpha[i] * l_i[i] + ls;
        }
        #pragma unroll
        for (int dc = 0; dc < 4; ++dc)
            #pragma unroll
            for (int i = 0; i < 4; ++i)
                o[dc][i] *= alpha[i];

        // ---- O += P V : wave reads ONLY its own P rows (no barrier) ----
        bf16x8 ap0 = *(const bf16x8*)&Ps[m * 64 + ((quad       ^ (m & 7)) * 8)];
        bf16x8 ap1 = *(const bf16x8*)&Ps[m * 64 + (((4 + quad) ^ (m & 7)) * 8)];
        #pragma unroll
        for (int dc = 0; dc < 4; ++dc) {
            int dr = dc * 16 + c;
            bf16x8 bv0 = *(const bf16x8*)&Vs[dr * 64 + ((quad       ^ (dr & 7)) * 8)];
            bf16x8 bv1 = *(const bf16x8*)&Vs[dr * 64 + (((4 + quad) ^ (dr & 7)) * 8)];
            o[dc] = __builtin_amdgcn_mfma_f32_16x16x32_bf16(ap0, bv0, o[dc], 0, 0, 0);
            o[dc] = __builtin_amdgcn_mfma_f32_16x16x32_bf16(ap1, bv1, o[dc], 0, 0, 0);
        }
    }

    // epilogue: O[b, q, h*64 + d] = o / l   (C-layout rows/cols)
    #pragma unroll
    for (int i = 0; i < 4; ++i) {
        float inv = 1.0f / l_i[i];
        int q = q0 + wv * 16 + quad * 4 + i;
        size_t rowoff = ((size_t)(b * NS + q)) * DIM + h * HD;
        #pragma unroll
        for (int dc = 0; dc < 4; ++dc)
            O[rowoff + dc * 16 + c] = o[dc][i] * inv;
    }
}

// ---------------------------------------------------------------------------
// Out projection: Z = ATT @ Wout^T + bout   (fp32)
// ---------------------------------------------------------------------------
__global__ __launch_bounds__(256) void out_gemm(
    const float* __restrict__ A, const float* __restrict__ W,
    const float* __restrict__ bias, float* __restrict__ Z)
{
    __shared__ float As[16][68];
    __shared__ float Bs[16][68];
    const int t = threadIdx.x;
    const int tx = t & 15, ty = t >> 4;
    const int m0 = blockIdx.x * 64;
    const int n0 = blockIdx.y * 64;
    float acc[4][4] = {};
    for (int k0 = 0; k0 < DIM; k0 += 16) {
        #pragma unroll
        for (int i = 0; i < 4; ++i) {
            int idx = i * 256 + t;
            int r = idx >> 4, c = idx & 15;
            As[c][r] = A[(size_t)(m0 + r) * DIM + k0 + c];
            Bs[c][r] = W[(size_t)(n0 + r) * DIM + k0 + c];
        }
        __syncthreads();
        #pragma unroll
        for (int kk = 0; kk < 16; ++kk) {
            float4 a4 = *(const float4*)&As[kk][ty * 4];
            float4 b4 = *(const float4*)&Bs[kk][tx * 4];
            float a[4] = {a4.x, a4.y, a4.z, a4.w};
            float b[4] = {b4.x, b4.y, b4.z, b4.w};
            #pragma unroll
            for (int i = 0; i < 4; ++i)
                #pragma unroll
                for (int j = 0; j < 4; ++j)
                    acc[i][j] += a[i] * b[j];
        }
        __syncthreads();
    }
    #pragma unroll
    for (int i = 0; i < 4; ++i) {
        int m = m0 + ty * 4 + i;
        #pragma unroll
        for (int j = 0; j < 4; ++j) {
            int n = n0 + tx * 4 + j;
            Z[(size_t)m * DIM + n] = acc[i][j] + bias[n];
        }
    }
}

// ---------------------------------------------------------------------------
// LayerNorm + ELU: one block of 256 threads per row of 512.
// ---------------------------------------------------------------------------
__global__ __launch_bounds__(256) void ln_elu(
    const float* __restrict__ Z, const float* __restrict__ g,
    const float* __restrict__ bt, float* __restrict__ out)
{
    const int row = blockIdx.x;
    const float* z = Z + (size_t)row * DIM;
    const int t = threadIdx.x;
    float v0 = z[t], v1 = z[t + 256];
    float s  = v0 + v1;
    float ss = v0 * v0 + v1 * v1;
    #pragma unroll
    for (int off = 32; off > 0; off >>= 1) {
        s  += __shfl_down(s, off);
        ss += __shfl_down(ss, off);
    }
    __shared__ float rs[4], rss[4];
    int wid = t >> 6, lane = t & 63;
    if (lane == 0) { rs[wid] = s; rss[wid] = ss; }
    __syncthreads();
    float S1 = rs[0] + rs[1] + rs[2] + rs[3];
    float S2 = rss[0] + rss[1] + rss[2] + rss[3];
    float mu  = S1 * (1.0f / DIM);
    float var = S2 * (1.0f / DIM) - mu * mu;
    float rstd = rsqrtf(var + 1e-5f);
    float y0 = (v0 - mu) * rstd * g[t]       + bt[t];
    float y1 = (v1 - mu) * rstd * g[t + 256] + bt[t + 256];
    out[(size_t)row * DIM + t]       = elu_f(y0);
    out[(size_t)row * DIM + t + 256] = elu_f(y1);
}

extern "C" void kernel_launch(void* const* d_in, const int* in_sizes, int n_in,
                              void* d_out, int out_size, void* d_ws, size_t ws_size,
                              hipStream_t stream)
{
    const float* x    = (const float*)d_in[0];
    const int*   mask = (const int*)d_in[1];
    const float* Wqkv = (const float*)d_in[2];
    const float* bqkv = (const float*)d_in[3];
    const float* Wout = (const float*)d_in[4];
    const float* bout = (const float*)d_in[5];
    const float* ln_g = (const float*)d_in[6];
    const float* ln_b = (const float*)d_in[7];
    float* out = (float*)d_out;

    const size_t QSZ = (size_t)NB * HEADS * NS * HD;   // 8388608 elements
    short* Qb  = (short*)d_ws;
    short* Kb  = Qb + QSZ;
    short* Vtb = Qb + 2 * QSZ;
    float* ATT = (float*)(Qb + 3 * QSZ);               // fp32, QSZ elements
    float* Zb  = ATT + QSZ;

    dim3 g1(256, 24);
    qkv_gemm<<<g1, 256, 0, stream>>>(x, Wqkv, bqkv, Qb, Kb, Vtb);
    attn_mfma<<<2048, 256, 0, stream>>>(Qb, Kb, Vtb, mask, ATT);
    dim3 g3(256, 8);
    out_gemm<<<g3, 256, 0, stream>>>(ATT, Wout, bout, Zb);
    ln_elu<<<NB * NS, 256, 0, stream>>>(Zb, ln_g, ln_b, out);
}

// Round 3
// 354.730 us; speedup vs baseline: 6.7226x; 2.2264x over previous
//
#include <hip/hip_runtime.h>

#define DIM 512
#define HEADS 8
#define HD 64
#define NB 8
#define NS 2048
#define SCALE_INV 0.125f
#define NEG_BIG -1e30f
#define QSZ 8388608   // NB*HEADS*NS*HD = NB*NS*DIM

typedef __attribute__((ext_vector_type(8))) short bf16x8;
typedef __attribute__((ext_vector_type(4))) float f32x4;

__device__ __forceinline__ float elu_f(float x) {
    return x > 0.0f ? x : (__expf(x) - 1.0f);
}
__device__ __forceinline__ short f2bf(float x) {            // RNE
    union { float f; unsigned u; } v; v.f = x;
    unsigned r = v.u + 0x7FFFu + ((v.u >> 16) & 1u);
    return (short)(r >> 16);
}
__device__ __forceinline__ short f2bf_t(float x) {          // truncate (P only)
    union { float f; unsigned u; } v; v.f = x;
    return (short)(v.u >> 16);
}

// ---------------------------------------------------------------------------
// prep: x->bf16; Wqkv rows permuted n=h*192+d*3+w -> n'=w*512+h*64+d, ->bf16;
// Wout->bf16; bqkv permuted (fp32).
// ---------------------------------------------------------------------------
#define X4 2097152            // x elems/4
#define W14 196608            // Wqkv elems/4
#define W24 65536             // Wout elems/4
__global__ __launch_bounds__(256) void prep(
    const float* __restrict__ x, const float* __restrict__ Wqkv,
    const float* __restrict__ bqkv, const float* __restrict__ Wout,
    short* __restrict__ xb, short* __restrict__ Wp,
    float* __restrict__ bp, short* __restrict__ Wob)
{
    int i = blockIdx.x * 256 + threadIdx.x;
    if (i < X4) {
        float4 v = *(const float4*)(x + (size_t)i * 4);
        ushort4 o; o.x = (unsigned short)f2bf(v.x); o.y = (unsigned short)f2bf(v.y);
        o.z = (unsigned short)f2bf(v.z); o.w = (unsigned short)f2bf(v.w);
        *(ushort4*)(xb + (size_t)i * 4) = o;
    } else if (i < X4 + W14) {
        int j = i - X4;
        int np = j >> 7, k = (j & 127) * 4;
        int w = np >> 9, h = (np >> 6) & 7, d = np & 63;
        int n = h * 192 + d * 3 + w;
        float4 v = *(const float4*)(Wqkv + (size_t)n * 512 + k);
        ushort4 o; o.x = (unsigned short)f2bf(v.x); o.y = (unsigned short)f2bf(v.y);
        o.z = (unsigned short)f2bf(v.z); o.w = (unsigned short)f2bf(v.w);
        *(ushort4*)(Wp + (size_t)np * 512 + k) = o;
    } else if (i < X4 + W14 + W24) {
        int j = i - X4 - W14;
        float4 v = *(const float4*)(Wout + (size_t)j * 4);
        ushort4 o; o.x = (unsigned short)f2bf(v.x); o.y = (unsigned short)f2bf(v.y);
        o.z = (unsigned short)f2bf(v.z); o.w = (unsigned short)f2bf(v.w);
        *(ushort4*)(Wob + (size_t)j * 4) = o;
    } else {
        int j = i - X4 - W14 - W24;   // 0..1535
        int w = j >> 9, h = (j >> 6) & 7, d = j & 63;
        bp[j] = bqkv[h * 192 + d * 3 + w];
    }
}

// ---------------------------------------------------------------------------
// QKV GEMM, bf16 MFMA 16x16x32, 128x128 tile, BK=64, 256 threads (2x2 waves).
// B = permuted Wqkv (row n' = [w][h][d], K-major). Epilogue:
//   w<2 : Q/K -> [b,h,s,d] bf16, coalesced 2B stores (d = nj*16+c).
//   w==2: ELU, transpose 128x128 via swizzled LDS, Vt -> [b,h,d,s] uint4 stores.
// ---------------------------------------------------------------------------
__global__ __launch_bounds__(256) void qkv_mfma(
    const short* __restrict__ A, const short* __restrict__ Bw,
    const float* __restrict__ bp, short* __restrict__ QKV)
{
    __shared__ short smem[2 * 128 * 64];
    short* As = smem;
    short* Bs = smem + 128 * 64;
    const int t = threadIdx.x, lane = t & 63, wv = t >> 6;
    const int c = lane & 15, quad = lane >> 4;
    const int wr = wv >> 1, wc = wv & 1;
    const int m0 = blockIdx.x * 128, n0 = blockIdx.y * 128;
    f32x4 acc[4][4];
    #pragma unroll
    for (int mi = 0; mi < 4; ++mi)
        #pragma unroll
        for (int nj = 0; nj < 4; ++nj)
            #pragma unroll
            for (int i = 0; i < 4; ++i) acc[mi][nj][i] = 0.0f;

    for (int k0 = 0; k0 < 512; k0 += 64) {
        if (k0) __syncthreads();
        #pragma unroll
        for (int p = 0; p < 4; ++p) {
            int idx = p * 256 + t, r = idx >> 3, cb = idx & 7;
            *(uint4*)&As[r * 64 + ((cb ^ (r & 7)) * 8)] =
                *(const uint4*)(A + (size_t)(m0 + r) * 512 + k0 + cb * 8);
            *(uint4*)&Bs[r * 64 + ((cb ^ (r & 7)) * 8)] =
                *(const uint4*)(Bw + (size_t)(n0 + r) * 512 + k0 + cb * 8);
        }
        __syncthreads();
        bf16x8 af[4][2], bfr[4][2];
        #pragma unroll
        for (int mi = 0; mi < 4; ++mi) {
            int ar = wr * 64 + mi * 16 + c;
            af[mi][0] = *(const bf16x8*)&As[ar * 64 + ((quad       ^ (ar & 7)) * 8)];
            af[mi][1] = *(const bf16x8*)&As[ar * 64 + (((4 + quad) ^ (ar & 7)) * 8)];
        }
        #pragma unroll
        for (int nj = 0; nj < 4; ++nj) {
            int br = wc * 64 + nj * 16 + c;
            bfr[nj][0] = *(const bf16x8*)&Bs[br * 64 + ((quad       ^ (br & 7)) * 8)];
            bfr[nj][1] = *(const bf16x8*)&Bs[br * 64 + (((4 + quad) ^ (br & 7)) * 8)];
        }
        #pragma unroll
        for (int mi = 0; mi < 4; ++mi)
            #pragma unroll
            for (int nj = 0; nj < 4; ++nj) {
                acc[mi][nj] = __builtin_amdgcn_mfma_f32_16x16x32_bf16(af[mi][0], bfr[nj][0], acc[mi][nj], 0, 0, 0);
                acc[mi][nj] = __builtin_amdgcn_mfma_f32_16x16x32_bf16(af[mi][1], bfr[nj][1], acc[mi][nj], 0, 0, 0);
            }
    }

    const int w  = n0 >> 9;                       // block-uniform
    const int b  = m0 >> 11;                      // block-uniform
    const int hh = ((n0 + wc * 64) >> 6) & 7;     // wave-uniform
    float bv[4];
    #pragma unroll
    for (int nj = 0; nj < 4; ++nj) bv[nj] = bp[n0 + wc * 64 + nj * 16 + c];

    if (w < 2) {
        short* out = QKV + (size_t)w * QSZ + (size_t)(b * 8 + hh) * NS * 64;
        #pragma unroll
        for (int mi = 0; mi < 4; ++mi)
            #pragma unroll
            for (int i = 0; i < 4; ++i) {
                int s = (m0 & (NS - 1)) + wr * 64 + mi * 16 + quad * 4 + i;
                #pragma unroll
                for (int nj = 0; nj < 4; ++nj)
                    out[(size_t)s * 64 + nj * 16 + c] = f2bf(acc[mi][nj][i] + bv[nj]);
            }
    } else {
        __syncthreads();                          // all frag ds_reads done
        short* T = smem;                          // 128x128 bf16, m-swizzled
        #pragma unroll
        for (int mi = 0; mi < 4; ++mi)
            #pragma unroll
            for (int i = 0; i < 4; ++i) {
                int ml = wr * 64 + mi * 16 + quad * 4 + i;
                int mb = ml >> 3, mr = ml & 7;
                #pragma unroll
                for (int nj = 0; nj < 4; ++nj) {
                    int nl = wc * 64 + nj * 16 + c;
                    T[nl * 128 + ((mb ^ (nl & 15)) * 8) + mr] =
                        f2bf(elu_f(acc[mi][nj][i] + bv[nj]));
                }
            }
        __syncthreads();
        short* Vt = QKV + (size_t)2 * QSZ;
        #pragma unroll
        for (int p = 0; p < 8; ++p) {
            int idx = p * 256 + t, row = idx >> 4, ch = idx & 15;
            uint4 v = *(const uint4*)&T[row * 128 + ((ch ^ (row & 15)) * 8)];
            int d = row & 63;
            int h2 = ((n0 + row) >> 6) & 7;
            *(uint4*)(Vt + ((size_t)(b * 8 + h2) * HD + d) * NS + (m0 & (NS - 1)) + ch * 8) = v;
        }
    }
}

// ---------------------------------------------------------------------------
// Flash attention, bf16 MFMA (unchanged core). Output now bf16; P truncated.
// ---------------------------------------------------------------------------
__global__ __launch_bounds__(256) void attn_mfma(
    const short* __restrict__ Qg, const short* __restrict__ Kg,
    const short* __restrict__ Vg, const int* __restrict__ mask,
    short* __restrict__ O)
{
    __shared__ short Qs[64 * 64];
    __shared__ short Ks[64 * 64];
    __shared__ short Vs[64 * 64];   // [d][k] (Vt tile)
    __shared__ short Ps[64 * 64];   // [q][k]
    __shared__ float msk[64];

    const int t = threadIdx.x;
    const int lane = t & 63;
    const int wv = t >> 6;
    const int c = lane & 15;
    const int quad = lane >> 4;
    const int bid = blockIdx.x;
    const int qt = bid & 31;
    const int h  = (bid >> 5) & 7;
    const int b  = bid >> 8;
    const size_t base = (size_t)(b * HEADS + h) * NS * HD;
    const int q0 = qt * 64;

    #pragma unroll
    for (int p = 0; p < 2; ++p) {
        int idx = p * 256 + t, r = idx >> 3, cb = idx & 7;
        uint4 v = *(const uint4*)(Qg + base + (size_t)(q0 + r) * HD + cb * 8);
        *(uint4*)&Qs[r * 64 + ((cb ^ (r & 7)) * 8)] = v;
    }
    __syncthreads();

    const int m = wv * 16 + c;
    const bf16x8 aq0 = *(const bf16x8*)&Qs[m * 64 + ((quad       ^ (m & 7)) * 8)];
    const bf16x8 aq1 = *(const bf16x8*)&Qs[m * 64 + (((4 + quad) ^ (m & 7)) * 8)];

    f32x4 o[4];
    #pragma unroll
    for (int dc = 0; dc < 4; ++dc)
        #pragma unroll
        for (int i = 0; i < 4; ++i) o[dc][i] = 0.0f;
    float m_i[4], l_i[4];
    #pragma unroll
    for (int i = 0; i < 4; ++i) { m_i[i] = NEG_BIG; l_i[i] = 0.0f; }

    for (int kt = 0; kt < 32; ++kt) {
        const int k0 = kt * 64;
        __syncthreads();
        #pragma unroll
        for (int p = 0; p < 2; ++p) {
            int idx = p * 256 + t, r = idx >> 3, cb = idx & 7;
            *(uint4*)&Ks[r * 64 + ((cb ^ (r & 7)) * 8)] =
                *(const uint4*)(Kg + base + (size_t)(k0 + r) * HD + cb * 8);
            *(uint4*)&Vs[r * 64 + ((cb ^ (r & 7)) * 8)] =
                *(const uint4*)(Vg + base + (size_t)r * NS + k0 + cb * 8);
        }
        if (t < 64) msk[t] = mask[b * NS + k0 + t] ? NEG_BIG : 0.0f;
        __syncthreads();

        f32x4 s4[4];
        #pragma unroll
        for (int nc = 0; nc < 4; ++nc) {
            int kr = nc * 16 + c;
            bf16x8 bk0 = *(const bf16x8*)&Ks[kr * 64 + ((quad       ^ (kr & 7)) * 8)];
            bf16x8 bk1 = *(const bf16x8*)&Ks[kr * 64 + (((4 + quad) ^ (kr & 7)) * 8)];
            f32x4 a = {0.0f, 0.0f, 0.0f, 0.0f};
            a = __builtin_amdgcn_mfma_f32_16x16x32_bf16(aq0, bk0, a, 0, 0, 0);
            a = __builtin_amdgcn_mfma_f32_16x16x32_bf16(aq1, bk1, a, 0, 0, 0);
            s4[nc] = a;
        }
        float bs[4];
        #pragma unroll
        for (int nc = 0; nc < 4; ++nc) bs[nc] = msk[nc * 16 + c];
        #pragma unroll
        for (int nc = 0; nc < 4; ++nc)
            #pragma unroll
            for (int i = 0; i < 4; ++i)
                s4[nc][i] = s4[nc][i] * SCALE_INV + bs[nc];

        float alpha[4], mn_r[4];
        #pragma unroll
        for (int i = 0; i < 4; ++i) {
            float rmax = fmaxf(fmaxf(s4[0][i], s4[1][i]), fmaxf(s4[2][i], s4[3][i]));
            #pragma unroll
            for (int off = 1; off < 16; off <<= 1)
                rmax = fmaxf(rmax, __shfl_xor(rmax, off));
            float mn = fmaxf(m_i[i], rmax);
            alpha[i] = __expf(m_i[i] - mn);
            mn_r[i] = mn;
            m_i[i] = mn;
        }
        #pragma unroll
        for (int i = 0; i < 4; ++i) {
            float ls = 0.0f;
            int r = wv * 16 + quad * 4 + i;
            #pragma unroll
            for (int nc = 0; nc < 4; ++nc) {
                float p = __expf(s4[nc][i] - mn_r[i]);
                ls += p;
                int col = nc * 16 + c;
                int cb = col >> 3;
                Ps[r * 64 + ((cb ^ (r & 7)) * 8) + (col & 7)] = f2bf_t(p);
            }
            #pragma unroll
            for (int off = 1; off < 16; off <<= 1)
                ls += __shfl_xor(ls, off);
            l_i[i] = alpha[i] * l_i[i] + ls;
        }
        #pragma unroll
        for (int dc = 0; dc < 4; ++dc)
            #pragma unroll
            for (int i = 0; i < 4; ++i)
                o[dc][i] *= alpha[i];

        bf16x8 ap0 = *(const bf16x8*)&Ps[m * 64 + ((quad       ^ (m & 7)) * 8)];
        bf16x8 ap1 = *(const bf16x8*)&Ps[m * 64 + (((4 + quad) ^ (m & 7)) * 8)];
        #pragma unroll
        for (int dc = 0; dc < 4; ++dc) {
            int dr = dc * 16 + c;
            bf16x8 bv0 = *(const bf16x8*)&Vs[dr * 64 + ((quad       ^ (dr & 7)) * 8)];
            bf16x8 bv1 = *(const bf16x8*)&Vs[dr * 64 + (((4 + quad) ^ (dr & 7)) * 8)];
            o[dc] = __builtin_amdgcn_mfma_f32_16x16x32_bf16(ap0, bv0, o[dc], 0, 0, 0);
            o[dc] = __builtin_amdgcn_mfma_f32_16x16x32_bf16(ap1, bv1, o[dc], 0, 0, 0);
        }
    }

    #pragma unroll
    for (int i = 0; i < 4; ++i) {
        float inv = 1.0f / l_i[i];
        int q = q0 + wv * 16 + quad * 4 + i;
        size_t rowoff = ((size_t)(b * NS + q)) * DIM + h * HD;
        #pragma unroll
        for (int dc = 0; dc < 4; ++dc)
            O[rowoff + dc * 16 + c] = f2bf(o[dc][i] * inv);
    }
}

// ---------------------------------------------------------------------------
// Out projection, bf16 MFMA: Z = ATT @ Wout^T + bout (fp32 out)
// ---------------------------------------------------------------------------
__global__ __launch_bounds__(256) void out_mfma(
    const short* __restrict__ A, const short* __restrict__ Bw,
    const float* __restrict__ bias, float* __restrict__ Z)
{
    __shared__ short smem[2 * 128 * 64];
    short* As = smem;
    short* Bs = smem + 128 * 64;
    const int t = threadIdx.x, lane = t & 63, wv = t >> 6;
    const int c = lane & 15, quad = lane >> 4;
    const int wr = wv >> 1, wc = wv & 1;
    const int m0 = blockIdx.x * 128, n0 = blockIdx.y * 128;
    f32x4 acc[4][4];
    #pragma unroll
    for (int mi = 0; mi < 4; ++mi)
        #pragma unroll
        for (int nj = 0; nj < 4; ++nj)
            #pragma unroll
            for (int i = 0; i < 4; ++i) acc[mi][nj][i] = 0.0f;

    for (int k0 = 0; k0 < 512; k0 += 64) {
        if (k0) __syncthreads();
        #pragma unroll
        for (int p = 0; p < 4; ++p) {
            int idx = p * 256 + t, r = idx >> 3, cb = idx & 7;
            *(uint4*)&As[r * 64 + ((cb ^ (r & 7)) * 8)] =
                *(const uint4*)(A + (size_t)(m0 + r) * 512 + k0 + cb * 8);
            *(uint4*)&Bs[r * 64 + ((cb ^ (r & 7)) * 8)] =
                *(const uint4*)(Bw + (size_t)(n0 + r) * 512 + k0 + cb * 8);
        }
        __syncthreads();
        bf16x8 af[4][2], bfr[4][2];
        #pragma unroll
        for (int mi = 0; mi < 4; ++mi) {
            int ar = wr * 64 + mi * 16 + c;
            af[mi][0] = *(const bf16x8*)&As[ar * 64 + ((quad       ^ (ar & 7)) * 8)];
            af[mi][1] = *(const bf16x8*)&As[ar * 64 + (((4 + quad) ^ (ar & 7)) * 8)];
        }
        #pragma unroll
        for (int nj = 0; nj < 4; ++nj) {
            int br = wc * 64 + nj * 16 + c;
            bfr[nj][0] = *(const bf16x8*)&Bs[br * 64 + ((quad       ^ (br & 7)) * 8)];
            bfr[nj][1] = *(const bf16x8*)&Bs[br * 64 + (((4 + quad) ^ (br & 7)) * 8)];
        }
        #pragma unroll
        for (int mi = 0; mi < 4; ++mi)
            #pragma unroll
            for (int nj = 0; nj < 4; ++nj) {
                acc[mi][nj] = __builtin_amdgcn_mfma_f32_16x16x32_bf16(af[mi][0], bfr[nj][0], acc[mi][nj], 0, 0, 0);
                acc[mi][nj] = __builtin_amdgcn_mfma_f32_16x16x32_bf16(af[mi][1], bfr[nj][1], acc[mi][nj], 0, 0, 0);
            }
    }
    #pragma unroll
    for (int mi = 0; mi < 4; ++mi)
        #pragma unroll
        for (int i = 0; i < 4; ++i) {
            int mrow = m0 + wr * 64 + mi * 16 + quad * 4 + i;
            #pragma unroll
            for (int nj = 0; nj < 4; ++nj) {
                int n = n0 + wc * 64 + nj * 16 + c;
                Z[(size_t)mrow * 512 + n] = acc[mi][nj][i] + bias[n];
            }
        }
}

// ---------------------------------------------------------------------------
// LayerNorm + ELU
// ---------------------------------------------------------------------------
__global__ __launch_bounds__(256) void ln_elu(
    const float* __restrict__ Z, const float* __restrict__ g,
    const float* __restrict__ bt, float* __restrict__ out)
{
    const int row = blockIdx.x;
    const float* z = Z + (size_t)row * DIM;
    const int t = threadIdx.x;
    float v0 = z[t], v1 = z[t + 256];
    float s  = v0 + v1;
    float ss = v0 * v0 + v1 * v1;
    #pragma unroll
    for (int off = 32; off > 0; off >>= 1) {
        s  += __shfl_down(s, off);
        ss += __shfl_down(ss, off);
    }
    __shared__ float rs[4], rss[4];
    int wid = t >> 6, lane = t & 63;
    if (lane == 0) { rs[wid] = s; rss[wid] = ss; }
    __syncthreads();
    float S1 = rs[0] + rs[1] + rs[2] + rs[3];
    float S2 = rss[0] + rss[1] + rss[2] + rss[3];
    float mu  = S1 * (1.0f / DIM);
    float var = S2 * (1.0f / DIM) - mu * mu;
    float rstd = rsqrtf(var + 1e-5f);
    float y0 = (v0 - mu) * rstd * g[t]       + bt[t];
    float y1 = (v1 - mu) * rstd * g[t + 256] + bt[t + 256];
    out[(size_t)row * DIM + t]       = elu_f(y0);
    out[(size_t)row * DIM + t + 256] = elu_f(y1);
}

extern "C" void kernel_launch(void* const* d_in, const int* in_sizes, int n_in,
                              void* d_out, int out_size, void* d_ws, size_t ws_size,
                              hipStream_t stream)
{
    const float* x    = (const float*)d_in[0];
    const int*   mask = (const int*)d_in[1];
    const float* Wqkv = (const float*)d_in[2];
    const float* bqkv = (const float*)d_in[3];
    const float* Wout = (const float*)d_in[4];
    const float* bout = (const float*)d_in[5];
    const float* ln_g = (const float*)d_in[6];
    const float* ln_b = (const float*)d_in[7];
    float* out = (float*)d_out;

    short* xb   = (short*)d_ws;           // QSZ
    short* Wp   = xb + QSZ;               // 786432
    short* Wob  = Wp + 786432;            // 262144
    short* QKV  = Wob + 262144;           // 3*QSZ  (Q | K | Vt)
    short* ATTb = QKV + 3 * (size_t)QSZ;  // QSZ
    float* bp   = (float*)(ATTb + QSZ);   // 1536
    float* Zb   = bp + 1536;              // QSZ floats

    prep<<<9222, 256, 0, stream>>>(x, Wqkv, bqkv, Wout, xb, Wp, bp, Wob);
    qkv_mfma<<<dim3(128, 12), 256, 0, stream>>>(xb, Wp, bp, QKV);
    attn_mfma<<<2048, 256, 0, stream>>>(QKV, QKV + QSZ, QKV + 2 * (size_t)QSZ, mask, ATTb);
    out_mfma<<<dim3(128, 4), 256, 0, stream>>>(ATTb, Wob, bout, Zb);
    ln_elu<<<NB * NS, 256, 0, stream>>>(Zb, ln_g, ln_b, out);
}